// Round 1
// baseline (1707.665 us; speedup 1.0000x reference)
//
#include <hip/hip_runtime.h>
#include <math.h>

#define INV_T 14.285714285714286f

// ---------------------------------------------------------------------------
// gemm_rb: C[2048x256] = epilogue(A[2048x256] @ B[256x256] + bias)
// epilogue: optional LN (over 256 cols), optional ReLU (after LN).
// grid 32 blocks x 256 threads; block computes 64 rows x full 256 cols.
// ---------------------------------------------------------------------------
__global__ __launch_bounds__(256) void gemm_rb(const float* __restrict__ A,
    const float* __restrict__ B, const float* __restrict__ bias,
    float* __restrict__ C, int do_ln, int do_relu)
{
    __shared__ float As[64][20];
    __shared__ float Bs[16][256];
    __shared__ float r1[64][17];
    __shared__ float r2[64][17];
    __shared__ float mrow[64];
    __shared__ float srow[64];
    const int tid = threadIdx.x;
    const int tx = tid & 15, ty = tid >> 4;
    const int row0 = blockIdx.x * 64;
    float acc[4][16];
#pragma unroll
    for (int i = 0; i < 4; i++)
#pragma unroll
        for (int j = 0; j < 16; j++) acc[i][j] = 0.f;

    const int arow = tid >> 2;
    const int acol = (tid & 3) * 4;
    for (int k0 = 0; k0 < 256; k0 += 16) {
        *(float4*)&As[arow][acol] =
            *(const float4*)(A + (size_t)(row0 + arow) * 256 + k0 + acol);
#pragma unroll
        for (int w = 0; w < 4; w++) {
            int idx = (w << 8) + tid;
            int br = idx >> 6;
            int bc = (idx & 63) << 2;
            *(float4*)&Bs[br][bc] = *(const float4*)(B + (size_t)(k0 + br) * 256 + bc);
        }
        __syncthreads();
#pragma unroll
        for (int kk = 0; kk < 16; kk++) {
            float a[4];
#pragma unroll
            for (int i = 0; i < 4; i++) a[i] = As[ty * 4 + i][kk];
#pragma unroll
            for (int j4 = 0; j4 < 4; j4++) {
                float4 b = *(const float4*)&Bs[kk][tx * 16 + j4 * 4];
#pragma unroll
                for (int i = 0; i < 4; i++) {
                    acc[i][j4 * 4 + 0] += a[i] * b.x;
                    acc[i][j4 * 4 + 1] += a[i] * b.y;
                    acc[i][j4 * 4 + 2] += a[i] * b.z;
                    acc[i][j4 * 4 + 3] += a[i] * b.w;
                }
            }
        }
        __syncthreads();
    }
    if (bias) {
#pragma unroll
        for (int j = 0; j < 16; j++) {
            float bv = bias[tx * 16 + j];
#pragma unroll
            for (int i = 0; i < 4; i++) acc[i][j] += bv;
        }
    }
    if (do_ln) {
#pragma unroll
        for (int i = 0; i < 4; i++) {
            float s = 0.f, s2 = 0.f;
#pragma unroll
            for (int j = 0; j < 16; j++) { float v = acc[i][j]; s += v; s2 += v * v; }
            r1[ty * 4 + i][tx] = s;
            r2[ty * 4 + i][tx] = s2;
        }
        __syncthreads();
        if (tid < 64) {
            float s = 0.f, s2 = 0.f;
#pragma unroll
            for (int t = 0; t < 16; t++) { s += r1[tid][t]; s2 += r2[tid][t]; }
            float m = s * (1.f / 256.f);
            float var = s2 * (1.f / 256.f) - m * m;
            mrow[tid] = m;
            srow[tid] = rsqrtf(var + 1e-5f);
        }
        __syncthreads();
#pragma unroll
        for (int i = 0; i < 4; i++) {
            float m = mrow[ty * 4 + i], is = srow[ty * 4 + i];
#pragma unroll
            for (int j = 0; j < 16; j++) {
                float v = (acc[i][j] - m) * is;
                if (do_relu) v = fmaxf(v, 0.f);
                acc[i][j] = v;
            }
        }
    }
#pragma unroll
    for (int i = 0; i < 4; i++) {
#pragma unroll
        for (int j4 = 0; j4 < 4; j4++) {
            float4 v = make_float4(acc[i][j4 * 4 + 0], acc[i][j4 * 4 + 1],
                                   acc[i][j4 * 4 + 2], acc[i][j4 * 4 + 3]);
            *(float4*)(C + (size_t)(row0 + ty * 4 + i) * 256 + tx * 16 + j4 * 4) = v;
        }
    }
}

// ---------------------------------------------------------------------------
// gemm_nn64: C[2048x256] = A[2048xK](row stride lda) @ B[Kx256] (+resid)
// grid (32,4), 64x64 tiles, 4x4 microtile.
// ---------------------------------------------------------------------------
__global__ __launch_bounds__(256) void gemm_nn64(const float* __restrict__ A, int lda,
    const float* __restrict__ B, const float* __restrict__ resid,
    float* __restrict__ C, int K)
{
    __shared__ float As[64][20];
    __shared__ float Bs[16][68];
    const int tid = threadIdx.x, tx = tid & 15, ty = tid >> 4;
    const int r0 = blockIdx.x * 64, c0 = blockIdx.y * 64;
    float acc[4][4];
#pragma unroll
    for (int i = 0; i < 4; i++)
#pragma unroll
        for (int j = 0; j < 4; j++) acc[i][j] = 0.f;

    const int arow = tid >> 2, acol = (tid & 3) * 4;
    const int brow = tid >> 4, bcol = (tid & 15) * 4;
    for (int k0 = 0; k0 < K; k0 += 16) {
        *(float4*)&As[arow][acol] =
            *(const float4*)(A + (size_t)(r0 + arow) * lda + k0 + acol);
        *(float4*)&Bs[brow][bcol] =
            *(const float4*)(B + (size_t)(k0 + brow) * 256 + c0 + bcol);
        __syncthreads();
#pragma unroll
        for (int kk = 0; kk < 16; kk++) {
            float a[4];
#pragma unroll
            for (int i = 0; i < 4; i++) a[i] = As[ty * 4 + i][kk];
            float4 b = *(const float4*)&Bs[kk][tx * 4];
#pragma unroll
            for (int i = 0; i < 4; i++) {
                acc[i][0] += a[i] * b.x;
                acc[i][1] += a[i] * b.y;
                acc[i][2] += a[i] * b.z;
                acc[i][3] += a[i] * b.w;
            }
        }
        __syncthreads();
    }
#pragma unroll
    for (int i = 0; i < 4; i++) {
        float4 v = make_float4(acc[i][0], acc[i][1], acc[i][2], acc[i][3]);
        if (resid) {
            float4 rv = *(const float4*)(resid + (size_t)(r0 + ty * 4 + i) * 256 + c0 + tx * 4);
            v.x += rv.x; v.y += rv.y; v.z += rv.z; v.w += rv.w;
        }
        *(float4*)(C + (size_t)(r0 + ty * 4 + i) * 256 + c0 + tx * 4) = v;
    }
}

// ---------------------------------------------------------------------------
// gemm_nt: C[2048x2048] = scale * A[2048x256] @ B[2048x256]^T
// grid (32,32): x = col tile, y = row tile.
// ---------------------------------------------------------------------------
__global__ __launch_bounds__(256) void gemm_nt(const float* __restrict__ A,
    const float* __restrict__ B, float* __restrict__ C, float scale)
{
    __shared__ float As[64][20];
    __shared__ float BsT[16][68];
    const int tid = threadIdx.x, tx = tid & 15, ty = tid >> 4;
    const int c0 = blockIdx.x * 64, r0 = blockIdx.y * 64;
    float acc[4][4];
#pragma unroll
    for (int i = 0; i < 4; i++)
#pragma unroll
        for (int j = 0; j < 4; j++) acc[i][j] = 0.f;

    const int arow = tid >> 2, acol = (tid & 3) * 4;
    for (int k0 = 0; k0 < 256; k0 += 16) {
        *(float4*)&As[arow][acol] =
            *(const float4*)(A + (size_t)(r0 + arow) * 256 + k0 + acol);
        float4 bv = *(const float4*)(B + (size_t)(c0 + arow) * 256 + k0 + acol);
        BsT[acol + 0][arow] = bv.x;
        BsT[acol + 1][arow] = bv.y;
        BsT[acol + 2][arow] = bv.z;
        BsT[acol + 3][arow] = bv.w;
        __syncthreads();
#pragma unroll
        for (int kk = 0; kk < 16; kk++) {
            float a[4];
#pragma unroll
            for (int i = 0; i < 4; i++) a[i] = As[ty * 4 + i][kk];
            float4 b = *(const float4*)&BsT[kk][tx * 4];
#pragma unroll
            for (int i = 0; i < 4; i++) {
                acc[i][0] += a[i] * b.x;
                acc[i][1] += a[i] * b.y;
                acc[i][2] += a[i] * b.z;
                acc[i][3] += a[i] * b.w;
            }
        }
        __syncthreads();
    }
#pragma unroll
    for (int i = 0; i < 4; i++) {
        float4 v = make_float4(acc[i][0] * scale, acc[i][1] * scale,
                               acc[i][2] * scale, acc[i][3] * scale);
        *(float4*)(C + (size_t)(r0 + ty * 4 + i) * 2048 + c0 + tx * 4) = v;
    }
}

// ---------------------------------------------------------------------------
// softmax_rows: in-place row softmax on S[2048x2048]; one block per row.
// ---------------------------------------------------------------------------
__global__ __launch_bounds__(256) void softmax_rows(float* __restrict__ S)
{
    const int tid = threadIdx.x;
    float* rp = S + (size_t)blockIdx.x * 2048;
    float4 x0 = ((float4*)rp)[tid];
    float4 x1 = ((float4*)rp)[tid + 256];
    float m = fmaxf(fmaxf(fmaxf(x0.x, x0.y), fmaxf(x0.z, x0.w)),
                    fmaxf(fmaxf(x1.x, x1.y), fmaxf(x1.z, x1.w)));
    __shared__ float red[4];
#pragma unroll
    for (int o = 32; o; o >>= 1) m = fmaxf(m, __shfl_xor(m, o));
    if ((tid & 63) == 0) red[tid >> 6] = m;
    __syncthreads();
    m = fmaxf(fmaxf(red[0], red[1]), fmaxf(red[2], red[3]));
    x0.x = __expf(x0.x - m); x0.y = __expf(x0.y - m);
    x0.z = __expf(x0.z - m); x0.w = __expf(x0.w - m);
    x1.x = __expf(x1.x - m); x1.y = __expf(x1.y - m);
    x1.z = __expf(x1.z - m); x1.w = __expf(x1.w - m);
    float s = x0.x + x0.y + x0.z + x0.w + x1.x + x1.y + x1.z + x1.w;
    __syncthreads();
#pragma unroll
    for (int o = 32; o; o >>= 1) s += __shfl_xor(s, o);
    if ((tid & 63) == 0) red[tid >> 6] = s;
    __syncthreads();
    s = red[0] + red[1] + red[2] + red[3];
    float inv = 1.f / s;
    x0.x *= inv; x0.y *= inv; x0.z *= inv; x0.w *= inv;
    x1.x *= inv; x1.y *= inv; x1.z *= inv; x1.w *= inv;
    ((float4*)rp)[tid] = x0;
    ((float4*)rp)[tid + 256] = x1;
}

// ---------------------------------------------------------------------------
// Sinkhorn row pass: la[r][:] = (la[r][:] - cl[:]) - LSE_row(la[r][:] - cl[:])
// ---------------------------------------------------------------------------
__global__ __launch_bounds__(256) void sink_row(float* __restrict__ la,
                                                const float* __restrict__ cl)
{
    const int tid = threadIdx.x;
    float* rp = la + (size_t)blockIdx.x * 2048;
    float4 x0 = ((float4*)rp)[tid];
    float4 x1 = ((float4*)rp)[tid + 256];
    float4 c0 = ((const float4*)cl)[tid];
    float4 c1 = ((const float4*)cl)[tid + 256];
    x0.x -= c0.x; x0.y -= c0.y; x0.z -= c0.z; x0.w -= c0.w;
    x1.x -= c1.x; x1.y -= c1.y; x1.z -= c1.z; x1.w -= c1.w;
    float m = fmaxf(fmaxf(fmaxf(x0.x, x0.y), fmaxf(x0.z, x0.w)),
                    fmaxf(fmaxf(x1.x, x1.y), fmaxf(x1.z, x1.w)));
    __shared__ float red[4];
#pragma unroll
    for (int o = 32; o; o >>= 1) m = fmaxf(m, __shfl_xor(m, o));
    if ((tid & 63) == 0) red[tid >> 6] = m;
    __syncthreads();
    m = fmaxf(fmaxf(red[0], red[1]), fmaxf(red[2], red[3]));
    float s = __expf(x0.x - m) + __expf(x0.y - m) + __expf(x0.z - m) + __expf(x0.w - m)
            + __expf(x1.x - m) + __expf(x1.y - m) + __expf(x1.z - m) + __expf(x1.w - m);
    __syncthreads();
#pragma unroll
    for (int o = 32; o; o >>= 1) s += __shfl_xor(s, o);
    if ((tid & 63) == 0) red[tid >> 6] = s;
    __syncthreads();
    s = red[0] + red[1] + red[2] + red[3];
    float lse = m + __logf(s);
    x0.x -= lse; x0.y -= lse; x0.z -= lse; x0.w -= lse;
    x1.x -= lse; x1.y -= lse; x1.z -= lse; x1.w -= lse;
    ((float4*)rp)[tid] = x0;
    ((float4*)rp)[tid + 256] = x1;
}

// Column LSE partials: grid (8 col groups, 32 row chunks of 64).
__global__ __launch_bounds__(256) void sink_colpart(const float* __restrict__ la,
    float* __restrict__ pm, float* __restrict__ ps)
{
    const int c = blockIdx.x * 256 + threadIdx.x;
    const int r0 = blockIdx.y * 64;
    float m = -3.402823466e38f;
    for (int r = 0; r < 64; r++)
        m = fmaxf(m, la[(size_t)(r0 + r) * 2048 + c]);
    float s = 0.f;
    for (int r = 0; r < 64; r++)
        s += __expf(la[(size_t)(r0 + r) * 2048 + c] - m);
    pm[blockIdx.y * 2048 + c] = m;
    ps[blockIdx.y * 2048 + c] = s;
}

__global__ __launch_bounds__(256) void sink_colcomb(const float* __restrict__ pm,
    const float* __restrict__ ps, float* __restrict__ cl)
{
    const int c = blockIdx.x * 256 + threadIdx.x;
    float M = -3.402823466e38f;
    for (int i = 0; i < 32; i++) M = fmaxf(M, pm[i * 2048 + c]);
    float S = 0.f;
    for (int i = 0; i < 32; i++) S += ps[i * 2048 + c] * __expf(pm[i * 2048 + c] - M);
    cl[c] = M + __logf(S);
}

// ---------------------------------------------------------------------------
// Instance-norm stats for M (sum, sumsq) and application.
// ---------------------------------------------------------------------------
__global__ __launch_bounds__(256) void reduce_stats(const float* __restrict__ M,
                                                    float* __restrict__ sc)
{
    const int gid = blockIdx.x * 256 + threadIdx.x;
    float s = 0.f, s2 = 0.f;
#pragma unroll
    for (int k = 0; k < 4; k++) {
        float4 v = ((const float4*)M)[gid + k * 262144];
        s += v.x + v.y + v.z + v.w;
        s2 += v.x * v.x + v.y * v.y + v.z * v.z + v.w * v.w;
    }
    __shared__ float red[8];
#pragma unroll
    for (int o = 32; o; o >>= 1) { s += __shfl_xor(s, o); s2 += __shfl_xor(s2, o); }
    if ((threadIdx.x & 63) == 0) {
        red[threadIdx.x >> 6] = s;
        red[4 + (threadIdx.x >> 6)] = s2;
    }
    __syncthreads();
    if (threadIdx.x == 0) {
        atomicAdd(&sc[0], red[0] + red[1] + red[2] + red[3]);
        atomicAdd(&sc[1], red[4] + red[5] + red[6] + red[7]);
    }
}

__global__ void finalize_stats(float* __restrict__ sc)
{
    if (threadIdx.x == 0 && blockIdx.x == 0) {
        float mean = sc[0] * (1.f / 4194304.f);
        float var = sc[1] * (1.f / 4194304.f) - mean * mean;
        sc[2] = mean;
        sc[3] = 1.f / (sqrtf(fmaxf(var, 0.f)) + 1e-5f);
    }
}

__global__ __launch_bounds__(256) void apply_norm(float* __restrict__ M,
                                                  const float* __restrict__ sc)
{
    const int gid = blockIdx.x * 256 + threadIdx.x;
    const float mean = sc[2], scale = sc[3];
#pragma unroll
    for (int k = 0; k < 4; k++) {
        float4 v = ((float4*)M)[gid + k * 262144];
        v.x = (v.x - mean) * scale; v.y = (v.y - mean) * scale;
        v.z = (v.z - mean) * scale; v.w = (v.w - mean) * scale;
        ((float4*)M)[gid + k * 262144] = v;
    }
}

// ---------------------------------------------------------------------------
// Match loss: sum |exp(la - cl[c]) - gt| -> sc[4]
// ---------------------------------------------------------------------------
__global__ __launch_bounds__(256) void match_loss(const float* __restrict__ la,
    const float* __restrict__ cl, const int* __restrict__ ls,
    const int* __restrict__ lt, float* __restrict__ sc)
{
    const int gid = blockIdx.x * 256 + threadIdx.x;
    float s = 0.f;
#pragma unroll
    for (int k = 0; k < 4; k++) {
        int idx4 = gid + k * 262144;
        int flat = idx4 * 4;
        int r = flat >> 11, c = flat & 2047;
        float4 v = ((const float4*)la)[idx4];
        int lr = ls[r];
        float p;
        p = __expf(v.x - cl[c + 0]); s += fabsf(p - ((lr == lt[c + 0]) ? 1.f : 0.f));
        p = __expf(v.y - cl[c + 1]); s += fabsf(p - ((lr == lt[c + 1]) ? 1.f : 0.f));
        p = __expf(v.z - cl[c + 2]); s += fabsf(p - ((lr == lt[c + 2]) ? 1.f : 0.f));
        p = __expf(v.w - cl[c + 3]); s += fabsf(p - ((lr == lt[c + 3]) ? 1.f : 0.f));
    }
    __shared__ float red[4];
#pragma unroll
    for (int o = 32; o; o >>= 1) s += __shfl_xor(s, o);
    if ((threadIdx.x & 63) == 0) red[threadIdx.x >> 6] = s;
    __syncthreads();
    if (threadIdx.x == 0) atomicAdd(&sc[4], red[0] + red[1] + red[2] + red[3]);
}

// ---------------------------------------------------------------------------
// feats: L2-normalize rows of concat(src2, tgt2) -> f[4096x256]; wave per row.
// ---------------------------------------------------------------------------
__global__ __launch_bounds__(256) void make_feats(const float* __restrict__ s2,
    const float* __restrict__ t2, float* __restrict__ f)
{
    const int row = blockIdx.x * 4 + (threadIdx.x >> 6);
    const int lane = threadIdx.x & 63;
    const float* src = (row < 2048) ? (s2 + (size_t)row * 256)
                                    : (t2 + (size_t)(row - 2048) * 256);
    float4 v = ((const float4*)src)[lane];
    float ss = v.x * v.x + v.y * v.y + v.z * v.z + v.w * v.w;
#pragma unroll
    for (int o = 32; o; o >>= 1) ss += __shfl_xor(ss, o);
    float inv = 1.f / (sqrtf(ss) + 1e-8f);
    v.x *= inv; v.y *= inv; v.z *= inv; v.w *= inv;
    ((float4*)(f + (size_t)row * 256))[lane] = v;
}

// ---------------------------------------------------------------------------
// Flash SupCon: rowmax is exactly 1/T (diag), so denominator/numerator are
// purely additive. grid (64 i-blocks, 4 j-splits of 1024). Accumulates
// dA[i] = sum_{j!=i} exp(l_ij - 1/T), sA[i] = sum_{match,j!=i} l_ij,
// nA[i] = n_pos_i  via atomics.
// ---------------------------------------------------------------------------
__global__ __launch_bounds__(256) void supcon_flash(const float* __restrict__ f,
    const int* __restrict__ ls, const int* __restrict__ lt,
    float* __restrict__ dA, float* __restrict__ sA, float* __restrict__ nA)
{
    __shared__ float As[64][20];
    __shared__ float BsT[16][68];
    __shared__ int Li[64];
    __shared__ float red[64][17];
    const int tid = threadIdx.x, tx = tid & 15, ty = tid >> 4;
    const int i0 = blockIdx.x * 64, j0b = blockIdx.y * 1024;
    if (tid < 64) Li[tid] = (i0 + tid < 2048) ? ls[i0 + tid] : lt[i0 + tid - 2048];
    __syncthreads();
    float dp[4] = {0.f, 0.f, 0.f, 0.f};
    float sp[4] = {0.f, 0.f, 0.f, 0.f};
    float np[4] = {0.f, 0.f, 0.f, 0.f};
    const int arow = tid >> 2, acol = (tid & 3) * 4;
    for (int jt = 0; jt < 16; jt++) {
        const int j0 = j0b + jt * 64;
        float acc[4][4];
#pragma unroll
        for (int i = 0; i < 4; i++)
#pragma unroll
            for (int j = 0; j < 4; j++) acc[i][j] = 0.f;
        for (int k0 = 0; k0 < 256; k0 += 16) {
            *(float4*)&As[arow][acol] =
                *(const float4*)(f + (size_t)(i0 + arow) * 256 + k0 + acol);
            float4 bv = *(const float4*)(f + (size_t)(j0 + arow) * 256 + k0 + acol);
            BsT[acol + 0][arow] = bv.x;
            BsT[acol + 1][arow] = bv.y;
            BsT[acol + 2][arow] = bv.z;
            BsT[acol + 3][arow] = bv.w;
            __syncthreads();
#pragma unroll
            for (int kk = 0; kk < 16; kk++) {
                float a[4];
#pragma unroll
                for (int i = 0; i < 4; i++) a[i] = As[ty * 4 + i][kk];
                float4 b = *(const float4*)&BsT[kk][tx * 4];
#pragma unroll
                for (int i = 0; i < 4; i++) {
                    acc[i][0] += a[i] * b.x;
                    acc[i][1] += a[i] * b.y;
                    acc[i][2] += a[i] * b.z;
                    acc[i][3] += a[i] * b.w;
                }
            }
            __syncthreads();
        }
        int lj[4];
#pragma unroll
        for (int jj = 0; jj < 4; jj++) {
            int j = j0 + tx * 4 + jj;
            lj[jj] = (j < 2048) ? ls[j] : lt[j - 2048];
        }
#pragma unroll
        for (int i = 0; i < 4; i++) {
            int gi = i0 + ty * 4 + i;
            int li = Li[ty * 4 + i];
#pragma unroll
            for (int jj = 0; jj < 4; jj++) {
                int gj = j0 + tx * 4 + jj;
                if (gj == gi) continue;
                float l = acc[i][jj] * INV_T;
                dp[i] += __expf(l - INV_T);
                if (lj[jj] == li) { sp[i] += l; np[i] += 1.f; }
            }
        }
    }
#pragma unroll
    for (int i = 0; i < 4; i++) red[ty * 4 + i][tx] = dp[i];
    __syncthreads();
    if (tid < 64) {
        float s = 0.f;
        for (int t = 0; t < 16; t++) s += red[tid][t];
        atomicAdd(&dA[i0 + tid], s);
    }
    __syncthreads();
#pragma unroll
    for (int i = 0; i < 4; i++) red[ty * 4 + i][tx] = sp[i];
    __syncthreads();
    if (tid < 64) {
        float s = 0.f;
        for (int t = 0; t < 16; t++) s += red[tid][t];
        atomicAdd(&sA[i0 + tid], s);
    }
    __syncthreads();
#pragma unroll
    for (int i = 0; i < 4; i++) red[ty * 4 + i][tx] = np[i];
    __syncthreads();
    if (tid < 64) {
        float s = 0.f;
        for (int t = 0; t < 16; t++) s += red[tid][t];
        atomicAdd(&nA[i0 + tid], s);
    }
}

__global__ __launch_bounds__(256) void supcon_rows(const float* __restrict__ dA,
    const float* __restrict__ sA, const float* __restrict__ nA,
    float* __restrict__ sc)
{
    const int i = blockIdx.x * 256 + threadIdx.x;
    float v = (INV_T + __logf(dA[i])) - sA[i] / nA[i];
    __shared__ float red[4];
#pragma unroll
    for (int o = 32; o; o >>= 1) v += __shfl_xor(v, o);
    if ((threadIdx.x & 63) == 0) red[threadIdx.x >> 6] = v;
    __syncthreads();
    if (threadIdx.x == 0) atomicAdd(&sc[5], red[0] + red[1] + red[2] + red[3]);
}

__global__ void zero_kernel(float* __restrict__ p, int n)
{
    int i = blockIdx.x * 256 + threadIdx.x;
    if (i < n) p[i] = 0.f;
}

__global__ void final_combine(const float* __restrict__ sc, float* __restrict__ out)
{
    if (threadIdx.x == 0 && blockIdx.x == 0)
        out[0] = sc[4] + 0.1f * (sc[5] * (1.f / 4096.f));
}

// ---------------------------------------------------------------------------
extern "C" void kernel_launch(void* const* d_in, const int* in_sizes, int n_in,
                              void* d_out, int out_size, void* d_ws, size_t ws_size,
                              hipStream_t stream)
{
    (void)in_sizes; (void)n_in; (void)out_size; (void)ws_size;
    const float* nodes_src = (const float*)d_in[0];
    const float* nodes_tgt = (const float*)d_in[1];
    const int* ls = (const int*)d_in[2];
    const int* lt = (const int*)d_in[3];
    const float* w1 = (const float*)d_in[4];
    const float* b1 = (const float*)d_in[5];
    const float* w2 = (const float*)d_in[6];
    const float* b2 = (const float*)d_in[7];
    const float* wq = (const float*)d_in[8];
    const float* wk = (const float*)d_in[9];
    const float* wv = (const float*)d_in[10];
    const float* wo = (const float*)d_in[11];
    const float* cq = (const float*)d_in[12];
    const float* ck = (const float*)d_in[13];
    const float* cv = (const float*)d_in[14];
    const float* co = (const float*)d_in[15];
    const float* Aw = (const float*)d_in[16];
    float* out = (float*)d_out;

    float* W = (float*)d_ws;
    const size_t NB = 524288; // 2048*256
    float* h_s = W;
    float* h_t = W + NB;
    float* s1 = W + 2 * NB;
    float* t1 = W + 3 * NB;
    float* s2 = W + 4 * NB;
    float* t2 = W + 5 * NB;
    float* qb = W + 6 * NB;
    float* kb = W + 7 * NB;
    float* vb = W + 8 * NB;
    float* pvb = W + 9 * NB;
    float* S = W + 10 * NB;        // 4194304 floats
    float* feats = S + 4194304;    // 1048576
    float* cl = feats + 1048576;   // 2048
    float* pm = cl + 2048;         // 65536
    float* ps = pm + 65536;        // 65536
    float* dA = ps + 65536;        // 4096
    float* sA = dA + 4096;
    float* nA = sA + 4096;
    float* sc = nA + 4096;         // 16

    const int zn = 2048 + 2 * 65536 + 3 * 4096 + 16;
    zero_kernel<<<(zn + 255) / 256, 256, 0, stream>>>(cl, zn);

    dim3 b256(256);
    // head_in for src and tgt
    gemm_rb<<<32, b256, 0, stream>>>(nodes_src, w1, b1, qb, 1, 1);
    gemm_rb<<<32, b256, 0, stream>>>(qb, w2, b2, h_s, 1, 0);
    gemm_rb<<<32, b256, 0, stream>>>(nodes_tgt, w1, b1, qb, 1, 1);
    gemm_rb<<<32, b256, 0, stream>>>(qb, w2, b2, h_t, 1, 0);

    auto attn = [&](const float* q_in, const float* kv_in,
                    const float* Wq, const float* Wk, const float* Wv, const float* Wo,
                    const float* res, float* outbuf) {
        gemm_nn64<<<dim3(32, 4), b256, 0, stream>>>(q_in, 256, Wq, nullptr, qb, 256);
        gemm_nn64<<<dim3(32, 4), b256, 0, stream>>>(kv_in, 256, Wk, nullptr, kb, 256);
        gemm_nn64<<<dim3(32, 4), b256, 0, stream>>>(kv_in, 256, Wv, nullptr, vb, 256);
        gemm_nt<<<dim3(32, 32), b256, 0, stream>>>(qb, kb, S, 0.0625f);
        softmax_rows<<<2048, b256, 0, stream>>>(S);
        gemm_nn64<<<dim3(32, 4), b256, 0, stream>>>(S, 2048, vb, nullptr, pvb, 2048);
        gemm_nn64<<<dim3(32, 4), b256, 0, stream>>>(pvb, 256, Wo, res, outbuf, 256);
    };
    attn(h_s, h_s, wq, wk, wv, wo, h_s, s1);   // intra src
    attn(h_t, h_t, wq, wk, wv, wo, h_t, t1);   // intra tgt
    attn(s1, t1, cq, ck, cv, co, s1, s2);      // cross src
    attn(t1, s1, cq, ck, cv, co, t1, t2);      // cross tgt

    // M = (s2 @ A) @ t2^T, instance-norm
    gemm_nn64<<<dim3(32, 4), b256, 0, stream>>>(s2, 256, Aw, nullptr, qb, 256);
    gemm_nt<<<dim3(32, 32), b256, 0, stream>>>(qb, t2, S, 1.0f);
    reduce_stats<<<1024, b256, 0, stream>>>(S, sc);
    finalize_stats<<<1, 1, 0, stream>>>(sc);
    apply_norm<<<1024, b256, 0, stream>>>(S, sc);

    // Sinkhorn (deferred column subtraction; cl starts at 0)
    for (int it = 0; it < 10; it++) {
        sink_row<<<2048, b256, 0, stream>>>(S, cl);
        sink_colpart<<<dim3(8, 32), b256, 0, stream>>>(S, pm, ps);
        sink_colcomb<<<8, b256, 0, stream>>>(pm, ps, cl);
    }
    match_loss<<<1024, b256, 0, stream>>>(S, cl, ls, lt, sc);

    // SupCon
    make_feats<<<1024, b256, 0, stream>>>(s2, t2, feats);
    supcon_flash<<<dim3(64, 4), b256, 0, stream>>>(feats, ls, lt, dA, sA, nA);
    supcon_rows<<<16, b256, 0, stream>>>(dA, sA, nA, sc);

    final_combine<<<1, 1, 0, stream>>>(sc, out);
}

// Round 2
// 822.944 us; speedup vs baseline: 2.0751x; 2.0751x over previous
//
#include <hip/hip_runtime.h>
#include <math.h>

#define INV_T 14.285714285714286f

typedef short v8s __attribute__((ext_vector_type(8)));
typedef short v4s __attribute__((ext_vector_type(4)));
typedef float v4f __attribute__((ext_vector_type(4)));

__device__ __forceinline__ float b2f(ushort u) {
    return __uint_as_float(((unsigned)u) << 16);
}
__device__ __forceinline__ ushort f2b(float f) {
    unsigned u = __float_as_uint(f);
    u += 0x7fff + ((u >> 16) & 1);
    return (ushort)(u >> 16);
}

// ---------------------------------------------------------------------------
// prep_w: jobs 0..7 transpose fp32 256x256 -> bf16 [n][k]; job 8 straight
// convert (A used untransposed). grid (16 tiles, 9 jobs).
// ---------------------------------------------------------------------------
struct W9 { const float* p[9]; };

__global__ __launch_bounds__(256) void prep_w(W9 w, ushort* __restrict__ dst)
{
    const int job = blockIdx.y;
    const float* __restrict__ src = w.p[job];
    ushort* __restrict__ d = dst + job * 65536;
    const int tile = blockIdx.x;
    const int tr = (tile >> 2) * 64, tc = (tile & 3) * 64;
    const int tid = threadIdx.x;
    if (job == 8) {
#pragma unroll
        for (int e = 0; e < 16; e++) {
            int r = tr + (tid >> 2);
            int col = tc + (tid & 3) * 16 + e;
            d[r * 256 + col] = f2b(src[r * 256 + col]);
        }
        return;
    }
    __shared__ float T[64][65];
#pragma unroll
    for (int e = 0; e < 16; e++) {
        int k = tr + (tid >> 6) + e * 4;
        int n = tc + (tid & 63);
        T[k - tr][n - tc] = src[k * 256 + n];
    }
    __syncthreads();
#pragma unroll
    for (int e = 0; e < 16; e++) {
        int n2 = tc + (tid >> 6) + e * 4;
        int k2 = tr + (tid & 63);
        d[n2 * 256 + k2] = f2b(T[k2 - tr][n2 - tc]);
    }
}

// ---------------------------------------------------------------------------
// gemm_rb (fp32, head_in only): C = epilogue(A @ B + bias), optional LN/ReLU,
// output fp32 or bf16. grid 32 x 256 thr; block = 64 rows x 256 cols.
// ---------------------------------------------------------------------------
__global__ __launch_bounds__(256) void gemm_rb(const float* __restrict__ A,
    const float* __restrict__ B, const float* __restrict__ bias,
    void* __restrict__ Cv, int do_relu, int out_bf16)
{
    __shared__ float As[64][20];
    __shared__ float Bs[16][256];
    __shared__ float r1[64][17];
    __shared__ float r2[64][17];
    __shared__ float mrow[64];
    __shared__ float srow[64];
    const int tid = threadIdx.x;
    const int tx = tid & 15, ty = tid >> 4;
    const int row0 = blockIdx.x * 64;
    float acc[4][16];
#pragma unroll
    for (int i = 0; i < 4; i++)
#pragma unroll
        for (int j = 0; j < 16; j++) acc[i][j] = 0.f;

    const int arow = tid >> 2;
    const int acol = (tid & 3) * 4;
    for (int k0 = 0; k0 < 256; k0 += 16) {
        *(float4*)&As[arow][acol] =
            *(const float4*)(A + (size_t)(row0 + arow) * 256 + k0 + acol);
#pragma unroll
        for (int w = 0; w < 4; w++) {
            int idx = (w << 8) + tid;
            int br = idx >> 6;
            int bc = (idx & 63) << 2;
            *(float4*)&Bs[br][bc] = *(const float4*)(B + (size_t)(k0 + br) * 256 + bc);
        }
        __syncthreads();
#pragma unroll
        for (int kk = 0; kk < 16; kk++) {
            float a[4];
#pragma unroll
            for (int i = 0; i < 4; i++) a[i] = As[ty * 4 + i][kk];
#pragma unroll
            for (int j4 = 0; j4 < 4; j4++) {
                float4 b = *(const float4*)&Bs[kk][tx * 16 + j4 * 4];
#pragma unroll
                for (int i = 0; i < 4; i++) {
                    acc[i][j4 * 4 + 0] += a[i] * b.x;
                    acc[i][j4 * 4 + 1] += a[i] * b.y;
                    acc[i][j4 * 4 + 2] += a[i] * b.z;
                    acc[i][j4 * 4 + 3] += a[i] * b.w;
                }
            }
        }
        __syncthreads();
    }
#pragma unroll
    for (int j = 0; j < 16; j++) {
        float bv = bias[tx * 16 + j];
#pragma unroll
        for (int i = 0; i < 4; i++) acc[i][j] += bv;
    }
    // LN always
#pragma unroll
    for (int i = 0; i < 4; i++) {
        float s = 0.f, s2 = 0.f;
#pragma unroll
        for (int j = 0; j < 16; j++) { float v = acc[i][j]; s += v; s2 += v * v; }
        r1[ty * 4 + i][tx] = s;
        r2[ty * 4 + i][tx] = s2;
    }
    __syncthreads();
    if (tid < 64) {
        float s = 0.f, s2 = 0.f;
#pragma unroll
        for (int t = 0; t < 16; t++) { s += r1[tid][t]; s2 += r2[tid][t]; }
        float m = s * (1.f / 256.f);
        float var = s2 * (1.f / 256.f) - m * m;
        mrow[tid] = m;
        srow[tid] = rsqrtf(var + 1e-5f);
    }
    __syncthreads();
#pragma unroll
    for (int i = 0; i < 4; i++) {
        float m = mrow[ty * 4 + i], is = srow[ty * 4 + i];
#pragma unroll
        for (int j = 0; j < 16; j++) {
            float v = (acc[i][j] - m) * is;
            if (do_relu) v = fmaxf(v, 0.f);
            acc[i][j] = v;
        }
    }
    if (out_bf16) {
        ushort* C = (ushort*)Cv;
#pragma unroll
        for (int i = 0; i < 4; i++)
#pragma unroll
            for (int j = 0; j < 16; j++)
                C[(size_t)(row0 + ty * 4 + i) * 256 + tx * 16 + j] = f2b(acc[i][j]);
    } else {
        float* C = (float*)Cv;
#pragma unroll
        for (int i = 0; i < 4; i++)
#pragma unroll
            for (int j4 = 0; j4 < 4; j4++) {
                float4 v = make_float4(acc[i][j4 * 4 + 0], acc[i][j4 * 4 + 1],
                                       acc[i][j4 * 4 + 2], acc[i][j4 * 4 + 3]);
                *(float4*)(C + (size_t)(row0 + ty * 4 + i) * 256 + tx * 16 + j4 * 4) = v;
            }
    }
}

// ---------------------------------------------------------------------------
// mfma_nt: C[M x N](bf16, ldc) = scale * A[M x K](bf16, lda) @ B[N x K]^T
//          (+ optional bf16 residual, stride ldc).
// grid (N/64, M/64), 256 thr = 4 waves, 64x64 block tile, 16x16x32 mfma.
// ---------------------------------------------------------------------------
__global__ __launch_bounds__(256) void mfma_nt(
    const ushort* __restrict__ A, int lda,
    const ushort* __restrict__ B, int ldb,
    ushort* __restrict__ C, int ldc,
    const ushort* __restrict__ resid,
    int K, float scale)
{
    __shared__ ushort As[64][40];
    __shared__ ushort Bs[64][40];
    const int tid = threadIdx.x;
    const int wave = tid >> 6, lane = tid & 63;
    const int g = lane >> 4, c = lane & 15;
    const int m0 = blockIdx.y * 64, n0 = blockIdx.x * 64;
    const int sr = tid >> 2, sk = (tid & 3) * 8;
    v4f acc[4] = {(v4f)(0.f), (v4f)(0.f), (v4f)(0.f), (v4f)(0.f)};
    for (int k0 = 0; k0 < K; k0 += 32) {
        *(v8s*)&As[sr][sk] = *(const v8s*)(A + (size_t)(m0 + sr) * lda + k0 + sk);
        *(v8s*)&Bs[sr][sk] = *(const v8s*)(B + (size_t)(n0 + sr) * ldb + k0 + sk);
        __syncthreads();
        v8s bfr = *(const v8s*)&Bs[wave * 16 + c][g * 8];
#pragma unroll
        for (int i = 0; i < 4; i++) {
            v8s afr = *(const v8s*)&As[i * 16 + c][g * 8];
            acc[i] = __builtin_amdgcn_mfma_f32_16x16x32_bf16(afr, bfr, acc[i], 0, 0, 0);
        }
        __syncthreads();
    }
#pragma unroll
    for (int i = 0; i < 4; i++) {
#pragma unroll
        for (int r = 0; r < 4; r++) {
            int row = m0 + i * 16 + g * 4 + r;
            int col = n0 + wave * 16 + c;
            float v = acc[i][r] * scale;
            if (resid) v += b2f(resid[(size_t)row * ldc + col]);
            C[(size_t)row * ldc + col] = f2b(v);
        }
    }
}

// ---------------------------------------------------------------------------
// softmax_bf: in-place row softmax, bf16 [2048 x 2048]; one block per row.
// ---------------------------------------------------------------------------
__global__ __launch_bounds__(256) void softmax_bf(ushort* __restrict__ S)
{
    const int tid = threadIdx.x;
    ushort* rp = S + (size_t)blockIdx.x * 2048;
    v8s v = *(const v8s*)(rp + tid * 8);
    float x[8];
#pragma unroll
    for (int j = 0; j < 8; j++) x[j] = b2f((ushort)v[j]);
    float m = x[0];
#pragma unroll
    for (int j = 1; j < 8; j++) m = fmaxf(m, x[j]);
    __shared__ float red[4];
#pragma unroll
    for (int o = 32; o; o >>= 1) m = fmaxf(m, __shfl_xor(m, o));
    if ((tid & 63) == 0) red[tid >> 6] = m;
    __syncthreads();
    m = fmaxf(fmaxf(red[0], red[1]), fmaxf(red[2], red[3]));
    float s = 0.f;
#pragma unroll
    for (int j = 0; j < 8; j++) { x[j] = __expf(x[j] - m); s += x[j]; }
    __syncthreads();
#pragma unroll
    for (int o = 32; o; o >>= 1) s += __shfl_xor(s, o);
    if ((tid & 63) == 0) red[tid >> 6] = s;
    __syncthreads();
    s = red[0] + red[1] + red[2] + red[3];
    float inv = 1.f / s;
    v8s o;
#pragma unroll
    for (int j = 0; j < 8; j++) o[j] = (short)f2b(x[j] * inv);
    *(v8s*)(rp + tid * 8) = o;
}

// ---------------------------------------------------------------------------
// reduce_stats: sum & sumsq of bf16 M -> sc[0], sc[1]
// ---------------------------------------------------------------------------
__global__ __launch_bounds__(256) void reduce_stats(const ushort* __restrict__ M,
                                                    float* __restrict__ sc)
{
    size_t base = ((size_t)blockIdx.x * 256 + threadIdx.x) * 16;
    float s = 0.f, s2 = 0.f;
#pragma unroll
    for (int h = 0; h < 2; h++) {
        v8s v = *(const v8s*)(M + base + h * 8);
#pragma unroll
        for (int j = 0; j < 8; j++) {
            float x = b2f((ushort)v[j]);
            s += x; s2 += x * x;
        }
    }
    __shared__ float red[8];
#pragma unroll
    for (int o = 32; o; o >>= 1) { s += __shfl_xor(s, o); s2 += __shfl_xor(s2, o); }
    if ((threadIdx.x & 63) == 0) {
        red[threadIdx.x >> 6] = s;
        red[4 + (threadIdx.x >> 6)] = s2;
    }
    __syncthreads();
    if (threadIdx.x == 0) {
        atomicAdd(&sc[0], red[0] + red[1] + red[2] + red[3]);
        atomicAdd(&sc[1], red[4] + red[5] + red[6] + red[7]);
    }
}

__global__ void finalize_stats(float* __restrict__ sc)
{
    if (threadIdx.x == 0 && blockIdx.x == 0) {
        float mean = sc[0] * (1.f / 4194304.f);
        float var = sc[1] * (1.f / 4194304.f) - mean * mean;
        sc[2] = mean;
        sc[3] = 1.f / (sqrtf(fmaxf(var, 0.f)) + 1e-5f);
    }
}

// ---------------------------------------------------------------------------
// sink_row: mode 0: x = (M - mean)*iscale (instance norm fused, first iter)
//           mode 1: x = la - cl
// then x -= rowLSE(x); bf16 in-place.
// ---------------------------------------------------------------------------
__global__ __launch_bounds__(256) void sink_row(ushort* __restrict__ la,
    const float* __restrict__ cl, const float* __restrict__ sc, int mode)
{
    const int tid = threadIdx.x;
    ushort* rp = la + (size_t)blockIdx.x * 2048;
    v8s v = *(const v8s*)(rp + tid * 8);
    float x[8];
    if (mode == 0) {
        float mean = sc[2], isd = sc[3];
#pragma unroll
        for (int j = 0; j < 8; j++) x[j] = (b2f((ushort)v[j]) - mean) * isd;
    } else {
        float4 c0 = *(const float4*)(cl + tid * 8);
        float4 c1 = *(const float4*)(cl + tid * 8 + 4);
        x[0] = b2f((ushort)v[0]) - c0.x; x[1] = b2f((ushort)v[1]) - c0.y;
        x[2] = b2f((ushort)v[2]) - c0.z; x[3] = b2f((ushort)v[3]) - c0.w;
        x[4] = b2f((ushort)v[4]) - c1.x; x[5] = b2f((ushort)v[5]) - c1.y;
        x[6] = b2f((ushort)v[6]) - c1.z; x[7] = b2f((ushort)v[7]) - c1.w;
    }
    float m = x[0];
#pragma unroll
    for (int j = 1; j < 8; j++) m = fmaxf(m, x[j]);
    __shared__ float red[4];
#pragma unroll
    for (int o = 32; o; o >>= 1) m = fmaxf(m, __shfl_xor(m, o));
    if ((tid & 63) == 0) red[tid >> 6] = m;
    __syncthreads();
    m = fmaxf(fmaxf(red[0], red[1]), fmaxf(red[2], red[3]));
    float s = 0.f;
#pragma unroll
    for (int j = 0; j < 8; j++) s += __expf(x[j] - m);
    __syncthreads();
#pragma unroll
    for (int o = 32; o; o >>= 1) s += __shfl_xor(s, o);
    if ((tid & 63) == 0) red[tid >> 6] = s;
    __syncthreads();
    s = red[0] + red[1] + red[2] + red[3];
    float lse = m + __logf(s);
    v8s o;
#pragma unroll
    for (int j = 0; j < 8; j++) o[j] = (short)f2b(x[j] - lse);
    *(v8s*)(rp + tid * 8) = o;
}

// Column LSE partials (online): grid (8 col groups, 32 row chunks of 64).
__global__ __launch_bounds__(256) void sink_colpart(const ushort* __restrict__ la,
    float* __restrict__ pm, float* __restrict__ ps)
{
    const int c = blockIdx.x * 256 + threadIdx.x;
    const int r0 = blockIdx.y * 64;
    float m = -3.402823466e38f, s = 0.f;
    for (int r = 0; r < 64; r++) {
        float x = b2f(la[(size_t)(r0 + r) * 2048 + c]);
        float nm = fmaxf(m, x);
        s = s * __expf(m - nm) + __expf(x - nm);
        m = nm;
    }
    pm[blockIdx.y * 2048 + c] = m;
    ps[blockIdx.y * 2048 + c] = s;
}

__global__ __launch_bounds__(256) void sink_colcomb(const float* __restrict__ pm,
    const float* __restrict__ ps, float* __restrict__ cl)
{
    const int c = blockIdx.x * 256 + threadIdx.x;
    float M = -3.402823466e38f;
    for (int i = 0; i < 32; i++) M = fmaxf(M, pm[i * 2048 + c]);
    float S = 0.f;
    for (int i = 0; i < 32; i++) S += ps[i * 2048 + c] * __expf(pm[i * 2048 + c] - M);
    cl[c] = M + __logf(S);
}

// ---------------------------------------------------------------------------
// match_loss: sum |exp(la - cl[c]) - gt| -> sc[4]
// ---------------------------------------------------------------------------
__global__ __launch_bounds__(256) void match_loss(const ushort* __restrict__ la,
    const float* __restrict__ cl, const int* __restrict__ ls,
    const int* __restrict__ lt, float* __restrict__ sc)
{
    const size_t base = ((size_t)blockIdx.x * 256 + threadIdx.x) * 16;
    const int r = (int)(base >> 11);
    const int cbase = (int)(base & 2047);
    const int lr = ls[r];
    float s = 0.f;
#pragma unroll
    for (int h = 0; h < 2; h++) {
        v8s v = *(const v8s*)(la + base + h * 8);
#pragma unroll
        for (int j = 0; j < 8; j++) {
            int cc = cbase + h * 8 + j;
            float p = __expf(b2f((ushort)v[j]) - cl[cc]);
            s += fabsf(p - ((lr == lt[cc]) ? 1.f : 0.f));
        }
    }
    __shared__ float red[4];
#pragma unroll
    for (int o = 32; o; o >>= 1) s += __shfl_xor(s, o);
    if ((threadIdx.x & 63) == 0) red[threadIdx.x >> 6] = s;
    __syncthreads();
    if (threadIdx.x == 0) atomicAdd(&sc[4], red[0] + red[1] + red[2] + red[3]);
}

// ---------------------------------------------------------------------------
// make_feats: L2-normalize rows of concat(s2, t2) (bf16) -> feats bf16.
// ---------------------------------------------------------------------------
__global__ __launch_bounds__(256) void make_feats(const ushort* __restrict__ s2,
    const ushort* __restrict__ t2, ushort* __restrict__ f)
{
    const int row = blockIdx.x * 4 + (threadIdx.x >> 6);
    const int lane = threadIdx.x & 63;
    const ushort* src = (row < 2048) ? (s2 + (size_t)row * 256)
                                     : (t2 + (size_t)(row - 2048) * 256);
    v4s v = *(const v4s*)(src + lane * 4);
    float a0 = b2f((ushort)v[0]), a1 = b2f((ushort)v[1]);
    float a2 = b2f((ushort)v[2]), a3 = b2f((ushort)v[3]);
    float ss = a0 * a0 + a1 * a1 + a2 * a2 + a3 * a3;
#pragma unroll
    for (int o = 32; o; o >>= 1) ss += __shfl_xor(ss, o);
    float inv = 1.f / (sqrtf(ss) + 1e-8f);
    v4s o;
    o[0] = (short)f2b(a0 * inv); o[1] = (short)f2b(a1 * inv);
    o[2] = (short)f2b(a2 * inv); o[3] = (short)f2b(a3 * inv);
    *(v4s*)(f + (size_t)row * 256 + lane * 4) = o;
}

// ---------------------------------------------------------------------------
// hist9: class histogram of concat labels -> hist (float).
// ---------------------------------------------------------------------------
__global__ __launch_bounds__(256) void hist9(const int* __restrict__ ls,
    const int* __restrict__ lt, float* __restrict__ hist)
{
    __shared__ int h[9];
    if (threadIdx.x < 9) h[threadIdx.x] = 0;
    __syncthreads();
    for (int i = threadIdx.x; i < 2048; i += 256) {
        atomicAdd(&h[ls[i]], 1);
        atomicAdd(&h[lt[i]], 1);
    }
    __syncthreads();
    if (threadIdx.x < 9) hist[threadIdx.x] = (float)h[threadIdx.x];
}

// ---------------------------------------------------------------------------
// csum9: per-class feature sums csum[9][256] (f32). grid (9, 16).
// ---------------------------------------------------------------------------
__global__ __launch_bounds__(256) void csum9(const ushort* __restrict__ f,
    const int* __restrict__ ls, const int* __restrict__ lt,
    float* __restrict__ csum)
{
    const int cls = blockIdx.x;
    const int chunk = blockIdx.y;
    const int t = threadIdx.x;
    float acc = 0.f;
    for (int r = 0; r < 256; r++) {
        int row = chunk * 256 + r;
        int lab = (row < 2048) ? ls[row] : lt[row - 2048];
        if (lab == cls) acc += b2f(f[(size_t)row * 256 + t]);
    }
    atomicAdd(&csum[cls * 256 + t], acc);
}

// ---------------------------------------------------------------------------
// supcon_dp: dA[i] += sum_j exp(f_i.f_j/T - 1/T) over 64x64 tile (incl diag).
// grid (64 j, 64 i). MFMA 64x64 tile, K=256.
// ---------------------------------------------------------------------------
__global__ __launch_bounds__(256) void supcon_dp(const ushort* __restrict__ f,
    float* __restrict__ dA)
{
    __shared__ ushort As[64][40];
    __shared__ ushort Bs[64][40];
    __shared__ float red[64][5];
    const int tid = threadIdx.x;
    const int wave = tid >> 6, lane = tid & 63;
    const int g = lane >> 4, c = lane & 15;
    const int i0 = blockIdx.y * 64, j0 = blockIdx.x * 64;
    const int sr = tid >> 2, sk = (tid & 3) * 8;
    v4f acc[4] = {(v4f)(0.f), (v4f)(0.f), (v4f)(0.f), (v4f)(0.f)};
    for (int k0 = 0; k0 < 256; k0 += 32) {
        *(v8s*)&As[sr][sk] = *(const v8s*)(f + (size_t)(i0 + sr) * 256 + k0 + sk);
        *(v8s*)&Bs[sr][sk] = *(const v8s*)(f + (size_t)(j0 + sr) * 256 + k0 + sk);
        __syncthreads();
        v8s bfr = *(const v8s*)&Bs[wave * 16 + c][g * 8];
#pragma unroll
        for (int i = 0; i < 4; i++) {
            v8s afr = *(const v8s*)&As[i * 16 + c][g * 8];
            acc[i] = __builtin_amdgcn_mfma_f32_16x16x32_bf16(afr, bfr, acc[i], 0, 0, 0);
        }
        __syncthreads();
    }
#pragma unroll
    for (int i = 0; i < 4; i++) {
#pragma unroll
        for (int r = 0; r < 4; r++) {
            float v = __expf(acc[i][r] * INV_T - INV_T);
#pragma unroll
            for (int o = 1; o < 16; o <<= 1) v += __shfl_xor(v, o);
            if (c == 0) red[i * 16 + g * 4 + r][wave] = v;
        }
    }
    __syncthreads();
    if (tid < 64) {
        float s = red[tid][0] + red[tid][1] + red[tid][2] + red[tid][3];
        atomicAdd(&dA[i0 + tid], s);
    }
}

// ---------------------------------------------------------------------------
// supcon_final: per-row v = 1/T + log(dA-1) - (f.csum[l]-1)/T/np -> sc[5]
// grid 1024 x 256 (4 rows per block).
// ---------------------------------------------------------------------------
__global__ __launch_bounds__(256) void supcon_final(const ushort* __restrict__ f,
    const float* __restrict__ csum, const float* __restrict__ hist,
    const float* __restrict__ dA, const int* __restrict__ ls,
    const int* __restrict__ lt, float* __restrict__ sc)
{
    const int wave = threadIdx.x >> 6, lane = threadIdx.x & 63;
    const int row = blockIdx.x * 4 + wave;
    const int lab = (row < 2048) ? ls[row] : lt[row - 2048];
    v4s v = *(const v4s*)(f + (size_t)row * 256 + lane * 4);
    float4 cv = *(const float4*)(csum + lab * 256 + lane * 4);
    float dot = b2f((ushort)v[0]) * cv.x + b2f((ushort)v[1]) * cv.y
              + b2f((ushort)v[2]) * cv.z + b2f((ushort)v[3]) * cv.w;
#pragma unroll
    for (int o = 32; o; o >>= 1) dot += __shfl_xor(dot, o);
    __shared__ float red[4];
    if (lane == 0) {
        float np = hist[lab] - 1.f;
        float val = INV_T + __logf(dA[row] - 1.f) - (dot - 1.f) * INV_T / np;
        red[wave] = val;
    }
    __syncthreads();
    if (threadIdx.x == 0) atomicAdd(&sc[5], red[0] + red[1] + red[2] + red[3]);
}

__global__ void zero_kernel(float* __restrict__ p, int n)
{
    int i = blockIdx.x * 256 + threadIdx.x;
    if (i < n) p[i] = 0.f;
}

__global__ void final_combine(const float* __restrict__ sc, float* __restrict__ out)
{
    if (threadIdx.x == 0 && blockIdx.x == 0)
        out[0] = sc[4] + 0.1f * (sc[5] * (1.f / 4096.f));
}

// ---------------------------------------------------------------------------
extern "C" void kernel_launch(void* const* d_in, const int* in_sizes, int n_in,
                              void* d_out, int out_size, void* d_ws, size_t ws_size,
                              hipStream_t stream)
{
    (void)in_sizes; (void)n_in; (void)out_size; (void)ws_size;
    const float* nodes_src = (const float*)d_in[0];
    const float* nodes_tgt = (const float*)d_in[1];
    const int* ls = (const int*)d_in[2];
    const int* lt = (const int*)d_in[3];
    const float* w1 = (const float*)d_in[4];
    const float* b1 = (const float*)d_in[5];
    const float* w2 = (const float*)d_in[6];
    const float* b2 = (const float*)d_in[7];
    float* out = (float*)d_out;

    char* p = (char*)d_ws;
    auto alloc = [&](size_t bytes) {
        char* r = p;
        p += (bytes + 255) & ~(size_t)255;
        return r;
    };
    ushort* wt    = (ushort*)alloc(9 * 65536 * 2);
    float*  qbf   = (float*)alloc(2048 * 256 * 4);
    ushort* h_s   = (ushort*)alloc(2048 * 256 * 2);
    ushort* h_t   = (ushort*)alloc(2048 * 256 * 2);
    ushort* s1    = (ushort*)alloc(2048 * 256 * 2);
    ushort* t1    = (ushort*)alloc(2048 * 256 * 2);
    ushort* s2    = (ushort*)alloc(2048 * 256 * 2);
    ushort* t2    = (ushort*)alloc(2048 * 256 * 2);
    ushort* Qb    = (ushort*)alloc(2048 * 256 * 2);
    ushort* Kb    = (ushort*)alloc(2048 * 256 * 2);
    ushort* Vtb   = (ushort*)alloc(2048 * 256 * 2);
    ushort* PVb   = (ushort*)alloc(2048 * 256 * 2);
    ushort* S     = (ushort*)alloc((size_t)2048 * 2048 * 2);
    ushort* feats = (ushort*)alloc(4096 * 256 * 2);
    float*  zbase = (float*)alloc(8464 * 4);   // cl | dA | csum | sc
    float*  hist  = (float*)alloc(16 * 4);
    float*  pm    = (float*)alloc(65536 * 4);
    float*  ps    = (float*)alloc(65536 * 4);
    float* cl   = zbase;
    float* dA   = zbase + 2048;
    float* csum = zbase + 2048 + 4096;
    float* sc   = csum + 2304;

    // transposed weights: 0 wq,1 wk,2 wv,3 wo,4 cq,5 ck,6 cv,7 co,8 A(convert)
    W9 w9;
    for (int i = 0; i < 8; i++) w9.p[i] = (const float*)d_in[8 + i];
    w9.p[8] = (const float*)d_in[16];
    ushort* wqt = wt;
    ushort* wkt = wt + 65536;
    ushort* wvt = wt + 2 * 65536;
    ushort* wot = wt + 3 * 65536;
    ushort* cqt = wt + 4 * 65536;
    ushort* ckt = wt + 5 * 65536;
    ushort* cvt = wt + 6 * 65536;
    ushort* cot = wt + 7 * 65536;
    ushort* Ab  = wt + 8 * 65536;

    dim3 b256(256);
    prep_w<<<dim3(16, 9), b256, 0, stream>>>(w9, wt);
    zero_kernel<<<34, b256, 0, stream>>>(zbase, 8464);

    // head_in
    gemm_rb<<<32, b256, 0, stream>>>(nodes_src, w1, b1, qbf, 1, 0);
    gemm_rb<<<32, b256, 0, stream>>>(qbf, w2, b2, h_s, 0, 1);
    gemm_rb<<<32, b256, 0, stream>>>(nodes_tgt, w1, b1, qbf, 1, 0);
    gemm_rb<<<32, b256, 0, stream>>>(qbf, w2, b2, h_t, 0, 1);

    auto attn = [&](const ushort* q_in, const ushort* kv_in,
                    const ushort* Wqt, const ushort* Wkt, const ushort* Wvt,
                    const ushort* Wot, ushort* outbuf) {
        mfma_nt<<<dim3(4, 32), b256, 0, stream>>>(q_in, 256, Wqt, 256, Qb, 256, nullptr, 256, 1.f);
        mfma_nt<<<dim3(4, 32), b256, 0, stream>>>(kv_in, 256, Wkt, 256, Kb, 256, nullptr, 256, 1.f);
        mfma_nt<<<dim3(32, 4), b256, 0, stream>>>(Wvt, 256, kv_in, 256, Vtb, 2048, nullptr, 256, 1.f);
        mfma_nt<<<dim3(32, 32), b256, 0, stream>>>(Qb, 256, Kb, 256, S, 2048, nullptr, 256, 0.0625f);
        softmax_bf<<<2048, b256, 0, stream>>>(S);
        mfma_nt<<<dim3(4, 32), b256, 0, stream>>>(S, 2048, Vtb, 2048, PVb, 256, nullptr, 2048, 1.f);
        mfma_nt<<<dim3(4, 32), b256, 0, stream>>>(PVb, 256, Wot, 256, outbuf, 256, q_in, 256, 1.f);
    };
    attn(h_s, h_s, wqt, wkt, wvt, wot, s1);
    attn(h_t, h_t, wqt, wkt, wvt, wot, t1);
    attn(s1, t1, cqt, ckt, cvt, cot, s2);
    attn(t1, s1, cqt, ckt, cvt, cot, t2);

    // M = s2 @ A @ t2^T : B2[n][d] = sum_e t2[n][e] A[d][e];  M = NT(s2, B2)
    mfma_nt<<<dim3(4, 32), b256, 0, stream>>>(t2, 256, Ab, 256, Qb, 256, nullptr, 256, 1.f);
    mfma_nt<<<dim3(32, 32), b256, 0, stream>>>(s2, 256, Qb, 256, S, 2048, nullptr, 256, 1.f);

    reduce_stats<<<1024, b256, 0, stream>>>(S, sc);
    finalize_stats<<<1, 1, 0, stream>>>(sc);

    // Sinkhorn: 10 iterations, instance-norm fused into iter 0
    sink_row<<<2048, b256, 0, stream>>>(S, cl, sc, 0);
    sink_colpart<<<dim3(8, 32), b256, 0, stream>>>(S, pm, ps);
    sink_colcomb<<<8, b256, 0, stream>>>(pm, ps, cl);
    for (int it = 1; it < 10; it++) {
        sink_row<<<2048, b256, 0, stream>>>(S, cl, sc, 1);
        sink_colpart<<<dim3(8, 32), b256, 0, stream>>>(S, pm, ps);
        sink_colcomb<<<8, b256, 0, stream>>>(pm, ps, cl);
    }
    match_loss<<<1024, b256, 0, stream>>>(S, cl, ls, lt, sc);

    // SupCon
    make_feats<<<1024, b256, 0, stream>>>(s2, t2, feats);
    hist9<<<1, b256, 0, stream>>>(ls, lt, hist);
    csum9<<<dim3(9, 16), b256, 0, stream>>>(feats, ls, lt, csum);
    supcon_dp<<<dim3(64, 64), b256, 0, stream>>>(feats, dA);
    supcon_final<<<1024, b256, 0, stream>>>(feats, csum, hist, dA, ls, lt, sc);

    final_combine<<<1, 1, 0, stream>>>(sc, out);
}